// Round 1
// baseline (1862.730 us; speedup 1.0000x reference)
//
#include <hip/hip_runtime.h>
#include <math.h>

#define VOCAB 50000
#define EMB 300
#define NB 128
#define TQ 32
#define TD 4096
#define TOPK 20
#define NCHUNK 8            // blocks per batch along doc axis
#define TOKS_PER_BLOCK 512  // TD / NCHUNK
#define DD_TOK 64           // doc tokens staged per inner iteration
#define NITER (TOKS_PER_BLOCK / DD_TOK)  // 8

// ---------------- Kernel 1: per-row inverse norms of emb_table ----------------
__global__ __launch_bounds__(256) void rownorm_kernel(const float* __restrict__ emb,
                                                      float* __restrict__ invn) {
  int row = blockIdx.x * 4 + (threadIdx.x >> 6);
  if (row >= VOCAB) return;
  int lane = threadIdx.x & 63;
  float s = 0.f;
  for (int h = lane; h < EMB; h += 64) {
    float v = emb[row * EMB + h];
    s += v * v;
  }
#pragma unroll
  for (int off = 32; off; off >>= 1) s += __shfl_xor(s, off, 64);
  if (lane == 0) invn[row] = 1.0f / fmaxf(sqrtf(s), 1e-8f);
}

// ---------------- Kernel 2: cosine matrix + per-chunk top-k ----------------
// grid = (NCHUNK, NB), block = 256
__global__ __launch_bounds__(256) void cos_topk_kernel(
    const int* __restrict__ doc, const int* __restrict__ query,
    const float* __restrict__ emb, const float* __restrict__ invn,
    float* __restrict__ partial /* [NB][NCHUNK][TQ][TOPK] */) {
  __shared__ float qn[TQ * EMB];        // 38400 B, normalized query embs
  __shared__ float dd[DD_TOK * EMB];    // 76800 B, normalized doc embs
  __shared__ float cosbuf[TQ * DD_TOK]; // 8192 B
  __shared__ float topv[TQ * TOPK];     // 2560 B, sorted descending per q

  const int b = blockIdx.y;
  const int chunk = blockIdx.x;
  const int tid = (int)threadIdx.x;

  // stage normalized query embeddings
  for (int i = tid; i < TQ * EMB; i += 256) {
    int q = i / EMB, h = i - q * EMB;
    int tok = query[b * TQ + q];
    qn[i] = emb[tok * EMB + h] * invn[tok];
  }
  for (int i = tid; i < TQ * TOPK; i += 256) topv[i] = -2.0f;

  const int tq = tid >> 5;         // 0..7
  const int tt = (tid & 31) << 1;  // 0,2,...,62

  for (int it = 0; it < NITER; ++it) {
    const int t0 = chunk * TOKS_PER_BLOCK + it * DD_TOK;
    // stage normalized doc embeddings for DD_TOK tokens
    for (int i = tid; i < DD_TOK * EMB; i += 256) {
      int t = i / EMB, h = i - t * EMB;
      int tok = doc[b * TD + t0 + t];
      dd[i] = emb[tok * EMB + h] * invn[tok];
    }
    __syncthreads();  // A: dd (and on it==0, qn) ready; prev merge done

    // compute 4q x 2t dot products per thread, float4 LDS reads
    float acc[4][2];
#pragma unroll
    for (int j = 0; j < 4; ++j) {
      acc[j][0] = 0.f;
      acc[j][1] = 0.f;
    }
    for (int h = 0; h < EMB; h += 4) {
      float4 d0 = *(const float4*)&dd[tt * EMB + h];
      float4 d1 = *(const float4*)&dd[(tt + 1) * EMB + h];
#pragma unroll
      for (int j = 0; j < 4; ++j) {
        float4 qv = *(const float4*)&qn[(tq + 8 * j) * EMB + h];
        acc[j][0] += qv.x * d0.x + qv.y * d0.y + qv.z * d0.z + qv.w * d0.w;
        acc[j][1] += qv.x * d1.x + qv.y * d1.y + qv.z * d1.z + qv.w * d1.w;
      }
    }
#pragma unroll
    for (int j = 0; j < 4; ++j) {
      cosbuf[(tq + 8 * j) * DD_TOK + tt] = acc[j][0];
      cosbuf[(tq + 8 * j) * DD_TOK + tt + 1] = acc[j][1];
    }
    __syncthreads();  // B: cosbuf complete; dd reads complete

    // one thread per q merges 64 new values into its sorted top-20
    if (tid < TQ) {
      const int q = tid;
      float mn = topv[q * TOPK + TOPK - 1];
      for (int t = 0; t < DD_TOK; ++t) {
        float v = cosbuf[q * DD_TOK + t];
        if (v > mn) {
          int p = TOPK - 1;
          while (p > 0 && topv[q * TOPK + p - 1] < v) {
            topv[q * TOPK + p] = topv[q * TOPK + p - 1];
            --p;
          }
          topv[q * TOPK + p] = v;
          mn = topv[q * TOPK + TOPK - 1];
        }
      }
    }
    // no sync needed here: next staging writes dd only; sync A protects cosbuf
  }

  __syncthreads();
  for (int i = tid; i < TQ * TOPK; i += 256)
    partial[(b * NCHUNK + chunk) * TQ * TOPK + i] = topv[i];
}

// ---------------- Kernel 3: merge partials, FFW+tanh, gated softmax ----------------
// grid = NB, block = 64 (one wave)
__global__ __launch_bounds__(64) void finalize_kernel(
    const float* __restrict__ partial, const int* __restrict__ query,
    const float* __restrict__ qidf, const float* __restrict__ ffw_W,
    const float* __restrict__ ffw_b, const float* __restrict__ gates_W,
    const float* __restrict__ out_W, const float* __restrict__ out_b,
    float* __restrict__ out) {
  const int b = blockIdx.x;
  const int lane = (int)threadIdx.x;  // 0..63
  float ffw = 0.f;
  float logit = -3e38f;
  if (lane < TQ) {
    const int q = lane;
    int pos[NCHUNK];
#pragma unroll
    for (int c = 0; c < NCHUNK; ++c) pos[c] = 0;
    float s = 0.f;
    for (int k = 0; k < TOPK; ++k) {
      float best = -4.f;
      int bi = 0;
#pragma unroll
      for (int c = 0; c < NCHUNK; ++c) {
        float v = (pos[c] < TOPK)
                      ? partial[((b * NCHUNK + c) * TQ + q) * TOPK + pos[c]]
                      : -4.f;
        if (v > best) {
          best = v;
          bi = c;
        }
      }
#pragma unroll
      for (int c = 0; c < NCHUNK; ++c)
        if (c == bi) pos[c]++;
      s += best * ffw_W[k];
    }
    ffw = tanhf(s + ffw_b[0]);
    int tok = query[b * TQ + q];
    logit = qidf[b * TQ + q] * gates_W[0] + (tok == 0 ? -1e7f : 0.f);
  }
  // softmax across the wave (lanes >= 32 contribute exp(.)=0)
  float m = logit;
#pragma unroll
  for (int off = 32; off; off >>= 1) m = fmaxf(m, __shfl_xor(m, off, 64));
  float e = expf(logit - m);
  float num = e * ffw;
  float den = e;
#pragma unroll
  for (int off = 32; off; off >>= 1) {
    num += __shfl_xor(num, off, 64);
    den += __shfl_xor(den, off, 64);
  }
  if (lane == 0) out[b] = (num / den) * out_W[0] + out_b[0];
}

extern "C" void kernel_launch(void* const* d_in, const int* in_sizes, int n_in,
                              void* d_out, int out_size, void* d_ws, size_t ws_size,
                              hipStream_t stream) {
  const int* doc = (const int*)d_in[0];
  const int* query = (const int*)d_in[1];
  const float* qidf = (const float*)d_in[2];
  const float* emb = (const float*)d_in[3];
  const float* ffw_W = (const float*)d_in[4];
  const float* ffw_b = (const float*)d_in[5];
  const float* gates_W = (const float*)d_in[6];
  const float* out_W = (const float*)d_in[7];
  const float* out_b = (const float*)d_in[8];
  float* out = (float*)d_out;

  float* invn = (float*)d_ws;      // 50000 floats
  float* partial = invn + 50048;   // NB*NCHUNK*TQ*TOPK = 655360 floats

  rownorm_kernel<<<(VOCAB + 3) / 4, 256, 0, stream>>>(emb, invn);
  dim3 grid(NCHUNK, NB);
  cos_topk_kernel<<<grid, 256, 0, stream>>>(doc, query, emb, invn, partial);
  finalize_kernel<<<NB, 64, 0, stream>>>(partial, query, qidf, ffw_W, ffw_b,
                                         gates_W, out_W, out_b, out);
}

// Round 2
// 700.837 us; speedup vs baseline: 2.6579x; 2.6579x over previous
//
#include <hip/hip_runtime.h>
#include <math.h>

#define VOCAB 50000
#define EMB 300
#define NB 128
#define TQ 32
#define TD 4096
#define TOPK 20
#define NCHUNK 16            // blocks per batch along doc axis
#define TOKS_PER_BLOCK 256   // TD / NCHUNK; 4 waves x 64 tokens
#define NHC 75               // EMB / 4

// ---------------- Kernel 1: per-row inverse norms of emb_table ----------------
__global__ __launch_bounds__(256) void rownorm_kernel(const float* __restrict__ emb,
                                                      float* __restrict__ invn) {
  int row = blockIdx.x * 4 + (threadIdx.x >> 6);
  if (row >= VOCAB) return;
  int lane = threadIdx.x & 63;
  float s = 0.f;
  for (int h = lane; h < EMB; h += 64) {
    float v = emb[row * EMB + h];
    s += v * v;
  }
#pragma unroll
  for (int off = 32; off; off >>= 1) s += __shfl_xor(s, off, 64);
  if (lane == 0) invn[row] = 1.0f / fmaxf(sqrtf(s), 1e-8f);
}

// ---------------- Kernel 1b: normalized query embeddings, transposed ----------------
// qn_t layout: [b][hc][q][4]  (hc = h/4)  -> wave-uniform 512B slabs per (b,hc)
__global__ __launch_bounds__(256) void qprep_kernel(const int* __restrict__ query,
                                                    const float* __restrict__ emb,
                                                    const float* __restrict__ invn,
                                                    float* __restrict__ qn_t) {
  const int b = blockIdx.x;
  for (int i = (int)threadIdx.x; i < NHC * TQ; i += 256) {
    int hc = i >> 5, q = i & 31;
    int tok = query[b * TQ + q];
    float inv = invn[tok];
    float4 v = *(const float4*)(emb + (size_t)tok * EMB + hc * 4);
    float4 o;
    o.x = v.x * inv; o.y = v.y * inv; o.z = v.z * inv; o.w = v.w * inv;
    *(float4*)(qn_t + (((size_t)b * NHC + hc) * TQ + q) * 4) = o;
  }
}

// ---------------- Kernel 2: cosine + per-block top-k ----------------
// grid = (NCHUNK, NB), block = 256 (4 waves); each lane owns ONE doc token.
__global__ __launch_bounds__(256) void cos_topk_kernel(
    const int* __restrict__ doc, const float* __restrict__ emb,
    const float* __restrict__ invn, const float* __restrict__ qn_t,
    float* __restrict__ partial /* [NB][NCHUNK][TQ][TOPK] */) {
  __shared__ float costmp[4][64][33];  // pad 33: banks (t+q)%32, conflict-free
  __shared__ float topv[4][TQ][21];    // per-wave sorted-desc top-20 (+pad)

  const int b = blockIdx.y;
  const int chunk = blockIdx.x;
  const int tid = (int)threadIdx.x;
  const int wave = tid >> 6;
  const int lane = tid & 63;

  // init this wave's top lists
  if (lane < TQ) {
#pragma unroll
    for (int k = 0; k < TOPK; ++k) topv[wave][lane][k] = -2.0f;
  }

  const int t = chunk * TOKS_PER_BLOCK + wave * 64 + lane;
  const int tok = doc[b * TD + t];
  const float* __restrict__ drow = emb + (size_t)tok * EMB;
  const float inv_d = invn[tok];
  const float* __restrict__ qb = qn_t + (size_t)b * NHC * (TQ * 4);

  float acc[TQ];
#pragma unroll
  for (int qi = 0; qi < TQ; ++qi) acc[qi] = 0.f;

  // depth-2 prefetched streaming dot products: 128 FMA per 16B global load
  float4 dcur = *(const float4*)(drow);
  for (int hc = 0; hc < NHC; ++hc) {
    float4 dnxt;
    if (hc < NHC - 1) dnxt = *(const float4*)(drow + 4 * (hc + 1));
    const float* __restrict__ qc = qb + (size_t)hc * (TQ * 4);  // wave-uniform
#pragma unroll
    for (int qi = 0; qi < TQ; ++qi) {
      float a = acc[qi];
      a = fmaf(qc[qi * 4 + 0], dcur.x, a);
      a = fmaf(qc[qi * 4 + 1], dcur.y, a);
      a = fmaf(qc[qi * 4 + 2], dcur.z, a);
      a = fmaf(qc[qi * 4 + 3], dcur.w, a);
      acc[qi] = a;
    }
    dcur = dnxt;
  }

  // transpose: lane-owned token row -> LDS (conflict-free, pad 33)
#pragma unroll
  for (int qi = 0; qi < TQ; ++qi) costmp[wave][lane][qi] = acc[qi] * inv_d;
  __syncthreads();

  // per-wave top-20 merge: lane q scans 64 token values (banks (t+q)%32)
  if (lane < TQ) {
    const int q = lane;
    float* tv = &topv[wave][q][0];
    float mn = tv[TOPK - 1];
    for (int tt = 0; tt < 64; ++tt) {
      float v = costmp[wave][tt][q];
      if (v > mn) {
        int p = TOPK - 1;
        while (p > 0 && tv[p - 1] < v) {
          tv[p] = tv[p - 1];
          --p;
        }
        tv[p] = v;
        mn = tv[TOPK - 1];
      }
    }
  }
  __syncthreads();

  // combine 4 wave lists into topv[0] (sorted-desc inputs -> early break)
  if (tid < TQ) {
    const int q = tid;
    float* dst = &topv[0][q][0];
#pragma unroll
    for (int w = 1; w < 4; ++w) {
      for (int k = 0; k < TOPK; ++k) {
        float v = topv[w][q][k];
        if (v <= dst[TOPK - 1]) break;
        int p = TOPK - 1;
        while (p > 0 && dst[p - 1] < v) {
          dst[p] = dst[p - 1];
          --p;
        }
        dst[p] = v;
      }
    }
  }
  __syncthreads();

  for (int i = tid; i < TQ * TOPK; i += 256)
    partial[((size_t)(b * NCHUNK + chunk)) * (TQ * TOPK) + i] = topv[0][i / TOPK][i % TOPK];
}

// ---------------- Kernel 3: merge partials, FFW+tanh, gated softmax ----------------
__global__ __launch_bounds__(64) void finalize_kernel(
    const float* __restrict__ partial, const int* __restrict__ query,
    const float* __restrict__ qidf, const float* __restrict__ ffw_W,
    const float* __restrict__ ffw_b, const float* __restrict__ gates_W,
    const float* __restrict__ out_W, const float* __restrict__ out_b,
    float* __restrict__ out) {
  const int b = blockIdx.x;
  const int lane = (int)threadIdx.x;  // 0..63
  float ffw = 0.f;
  float logit = -3e38f;
  if (lane < TQ) {
    const int q = lane;
    int pos[NCHUNK];
#pragma unroll
    for (int c = 0; c < NCHUNK; ++c) pos[c] = 0;
    float s = 0.f;
    for (int k = 0; k < TOPK; ++k) {
      float best = -4.f;
      int bi = 0;
#pragma unroll
      for (int c = 0; c < NCHUNK; ++c) {
        float v = (pos[c] < TOPK)
                      ? partial[((size_t)(b * NCHUNK + c) * TQ + q) * TOPK + pos[c]]
                      : -4.f;
        if (v > best) {
          best = v;
          bi = c;
        }
      }
#pragma unroll
      for (int c = 0; c < NCHUNK; ++c)
        if (c == bi) pos[c]++;
      s += best * ffw_W[k];
    }
    ffw = tanhf(s + ffw_b[0]);
    int tok = query[b * TQ + q];
    logit = qidf[b * TQ + q] * gates_W[0] + (tok == 0 ? -1e7f : 0.f);
  }
  float m = logit;
#pragma unroll
  for (int off = 32; off; off >>= 1) m = fmaxf(m, __shfl_xor(m, off, 64));
  float e = expf(logit - m);
  float num = e * ffw;
  float den = e;
#pragma unroll
  for (int off = 32; off; off >>= 1) {
    num += __shfl_xor(num, off, 64);
    den += __shfl_xor(den, off, 64);
  }
  if (lane == 0) out[b] = (num / den) * out_W[0] + out_b[0];
}

extern "C" void kernel_launch(void* const* d_in, const int* in_sizes, int n_in,
                              void* d_out, int out_size, void* d_ws, size_t ws_size,
                              hipStream_t stream) {
  const int* doc = (const int*)d_in[0];
  const int* query = (const int*)d_in[1];
  const float* qidf = (const float*)d_in[2];
  const float* emb = (const float*)d_in[3];
  const float* ffw_W = (const float*)d_in[4];
  const float* ffw_b = (const float*)d_in[5];
  const float* gates_W = (const float*)d_in[6];
  const float* out_W = (const float*)d_in[7];
  const float* out_b = (const float*)d_in[8];
  float* out = (float*)d_out;

  float* invn = (float*)d_ws;                         // 50048 floats
  float* qn_t = invn + 50048;                         // 128*75*32*4 = 1228800
  float* partial = qn_t + (size_t)NB * NHC * TQ * 4;  // 128*16*32*20 = 1310720

  rownorm_kernel<<<(VOCAB + 3) / 4, 256, 0, stream>>>(emb, invn);
  qprep_kernel<<<NB, 256, 0, stream>>>(query, emb, invn, qn_t);
  dim3 grid(NCHUNK, NB);
  cos_topk_kernel<<<grid, 256, 0, stream>>>(doc, emb, invn, qn_t, partial);
  finalize_kernel<<<NB, 64, 0, stream>>>(partial, query, qidf, ffw_W, ffw_b,
                                         gates_W, out_W, out_b, out);
}

// Round 3
// 699.343 us; speedup vs baseline: 2.6635x; 1.0021x over previous
//
#include <hip/hip_runtime.h>
#include <math.h>

#define VOCAB 50000
#define EMB 300
#define NB 128
#define TQ 32
#define TD 4096
#define TOPK 20
#define NCHUNK 4             // blocks per batch along doc axis
#define TOKS_PER_BLOCK 1024  // TD / NCHUNK
#define NTOK 4               // doc tokens per lane
#define NHC 75               // EMB / 4

// ---------------- Kernel 1: per-row inverse norms of emb_table ----------------
__global__ __launch_bounds__(256) void rownorm_kernel(const float* __restrict__ emb,
                                                      float* __restrict__ invn) {
  int row = blockIdx.x * 4 + (threadIdx.x >> 6);
  if (row >= VOCAB) return;
  int lane = threadIdx.x & 63;
  float s = 0.f;
  for (int h = lane; h < EMB; h += 64) {
    float v = emb[row * EMB + h];
    s += v * v;
  }
#pragma unroll
  for (int off = 32; off; off >>= 1) s += __shfl_xor(s, off, 64);
  if (lane == 0) invn[row] = 1.0f / fmaxf(sqrtf(s), 1e-8f);
}

// ---------------- Kernel 1b: normalized query embeddings, transposed ----------------
// qn_t layout: [b][hc][q][4]  (hc = h/4) -> one contiguous 38.4KB slab per b
__global__ __launch_bounds__(256) void qprep_kernel(const int* __restrict__ query,
                                                    const float* __restrict__ emb,
                                                    const float* __restrict__ invn,
                                                    float* __restrict__ qn_t) {
  const int b = blockIdx.x;
  for (int i = (int)threadIdx.x; i < NHC * TQ; i += 256) {
    int hc = i >> 5, q = i & 31;
    int tok = query[b * TQ + q];
    float inv = invn[tok];
    float4 v = *(const float4*)(emb + (size_t)tok * EMB + hc * 4);
    float4 o;
    o.x = v.x * inv; o.y = v.y * inv; o.z = v.z * inv; o.w = v.w * inv;
    *(float4*)(qn_t + (((size_t)b * NHC + hc) * TQ + q) * 4) = o;
  }
}

// ---------------- Kernel 2: cosine + per-block top-k ----------------
// grid = (NCHUNK, NB), block = 256 (4 waves); each lane owns NTOK=4 doc tokens.
// LDS: union { qsh[9600] fp32 ; costmp[4][64][33] } + topv  = 48KB -> LDS 3 blk/CU,
// VGPR (~190) gates to 2 waves/SIMD; grid 512 = exactly 2 blocks/CU.
__global__ __launch_bounds__(256, 2) void cos_topk_kernel(
    const int* __restrict__ doc, const float* __restrict__ emb,
    const float* __restrict__ invn, const float* __restrict__ qn_t,
    float* __restrict__ partial /* [NB][NCHUNK][TQ][TOPK] */) {
  __shared__ __align__(16) float smem[9600];  // qsh, later reused as costmp
  __shared__ float topv[4][TQ][21];           // per-wave sorted-desc top-20

  float* qsh = smem;
  float (*costmp)[33] = (float (*)[33])smem;  // [wave*64 + tok][q], pad 33

  const int b = blockIdx.y;
  const int chunk = blockIdx.x;
  const int tid = (int)threadIdx.x;
  const int wave = tid >> 6;
  const int lane = tid & 63;

  // stage this batch's normalized query slab into LDS (linear copy, float4)
  {
    const float4* src = (const float4*)(qn_t + (size_t)b * (NHC * TQ * 4));
    float4* dst = (float4*)qsh;
    for (int i = tid; i < NHC * TQ; i += 256) dst[i] = src[i];
  }
  if (lane < TQ) {
#pragma unroll
    for (int k = 0; k < TOPK; ++k) topv[wave][lane][k] = -2.0f;
  }
  __syncthreads();  // qsh ready

  // each lane owns 4 tokens: chunk*1024 + j*256 + tid
  const int t0 = chunk * TOKS_PER_BLOCK;
  const float* __restrict__ drow[NTOK];
  float invd[NTOK];
#pragma unroll
  for (int j = 0; j < NTOK; ++j) {
    int tok = doc[b * TD + t0 + j * 256 + tid];
    drow[j] = emb + (size_t)tok * EMB;
    invd[j] = invn[tok];
  }

  float acc[NTOK][TQ];
#pragma unroll
  for (int j = 0; j < NTOK; ++j)
#pragma unroll
    for (int qi = 0; qi < TQ; ++qi) acc[j][qi] = 0.f;

  float4 dcur[NTOK], dnxt[NTOK];
#pragma unroll
  for (int j = 0; j < NTOK; ++j) dcur[j] = *(const float4*)(drow[j]);

  for (int hc = 0; hc < NHC; ++hc) {
    if (hc < NHC - 1) {
#pragma unroll
      for (int j = 0; j < NTOK; ++j)
        dnxt[j] = *(const float4*)(drow[j] + 4 * (hc + 1));
    }
    const float* __restrict__ qc = qsh + hc * (TQ * 4);
#pragma unroll
    for (int qi = 0; qi < TQ; ++qi) {
      float4 qf = *(const float4*)(qc + qi * 4);  // wave-uniform -> broadcast
#pragma unroll
      for (int j = 0; j < NTOK; ++j) {
        float a = acc[j][qi];
        a = fmaf(qf.x, dcur[j].x, a);
        a = fmaf(qf.y, dcur[j].y, a);
        a = fmaf(qf.z, dcur[j].z, a);
        a = fmaf(qf.w, dcur[j].w, a);
        acc[j][qi] = a;
      }
    }
#pragma unroll
    for (int j = 0; j < NTOK; ++j) dcur[j] = dnxt[j];
  }

  __syncthreads();  // all waves done reading qsh; safe to overwrite with costmp

  // 4 passes: transpose 64 tokens (this wave's token j) -> merge into wave top-20
#pragma unroll 1
  for (int j = 0; j < NTOK; ++j) {
#pragma unroll
    for (int qi = 0; qi < TQ; ++qi)
      costmp[wave * 64 + lane][qi] = acc[j][qi] * invd[j];
    // per-wave region is private; lanes of this wave proceed in lockstep
    if (lane < TQ) {
      const int q = lane;
      float* tv = &topv[wave][q][0];
      float mn = tv[TOPK - 1];
      for (int tt = 0; tt < 64; ++tt) {
        float v = costmp[wave * 64 + tt][q];
        if (v > mn) {
          int p = TOPK - 1;
          while (p > 0 && tv[p - 1] < v) {
            tv[p] = tv[p - 1];
            --p;
          }
          tv[p] = v;
          mn = tv[TOPK - 1];
        }
      }
    }
  }
  __syncthreads();

  // combine 4 wave lists into topv[0]
  if (tid < TQ) {
    const int q = tid;
    float* dst = &topv[0][q][0];
#pragma unroll
    for (int w = 1; w < 4; ++w) {
      for (int k = 0; k < TOPK; ++k) {
        float v = topv[w][q][k];
        if (v <= dst[TOPK - 1]) break;
        int p = TOPK - 1;
        while (p > 0 && dst[p - 1] < v) {
          dst[p] = dst[p - 1];
          --p;
        }
        dst[p] = v;
      }
    }
  }
  __syncthreads();

  for (int i = tid; i < TQ * TOPK; i += 256)
    partial[((size_t)(b * NCHUNK + chunk)) * (TQ * TOPK) + i] =
        topv[0][i / TOPK][i % TOPK];
}

// ---------------- Kernel 3: merge partials, FFW+tanh, gated softmax ----------------
__global__ __launch_bounds__(64) void finalize_kernel(
    const float* __restrict__ partial, const int* __restrict__ query,
    const float* __restrict__ qidf, const float* __restrict__ ffw_W,
    const float* __restrict__ ffw_b, const float* __restrict__ gates_W,
    const float* __restrict__ out_W, const float* __restrict__ out_b,
    float* __restrict__ out) {
  const int b = blockIdx.x;
  const int lane = (int)threadIdx.x;  // 0..63
  float ffw = 0.f;
  float logit = -3e38f;
  if (lane < TQ) {
    const int q = lane;
    int pos[NCHUNK];
#pragma unroll
    for (int c = 0; c < NCHUNK; ++c) pos[c] = 0;
    float s = 0.f;
    for (int k = 0; k < TOPK; ++k) {
      float best = -4.f;
      int bi = 0;
#pragma unroll
      for (int c = 0; c < NCHUNK; ++c) {
        float v = (pos[c] < TOPK)
                      ? partial[((size_t)(b * NCHUNK + c) * TQ + q) * TOPK + pos[c]]
                      : -4.f;
        if (v > best) {
          best = v;
          bi = c;
        }
      }
#pragma unroll
      for (int c = 0; c < NCHUNK; ++c)
        if (c == bi) pos[c]++;
      s += best * ffw_W[k];
    }
    ffw = tanhf(s + ffw_b[0]);
    int tok = query[b * TQ + q];
    logit = qidf[b * TQ + q] * gates_W[0] + (tok == 0 ? -1e7f : 0.f);
  }
  float m = logit;
#pragma unroll
  for (int off = 32; off; off >>= 1) m = fmaxf(m, __shfl_xor(m, off, 64));
  float e = expf(logit - m);
  float num = e * ffw;
  float den = e;
#pragma unroll
  for (int off = 32; off; off >>= 1) {
    num += __shfl_xor(num, off, 64);
    den += __shfl_xor(den, off, 64);
  }
  if (lane == 0) out[b] = (num / den) * out_W[0] + out_b[0];
}

extern "C" void kernel_launch(void* const* d_in, const int* in_sizes, int n_in,
                              void* d_out, int out_size, void* d_ws, size_t ws_size,
                              hipStream_t stream) {
  const int* doc = (const int*)d_in[0];
  const int* query = (const int*)d_in[1];
  const float* qidf = (const float*)d_in[2];
  const float* emb = (const float*)d_in[3];
  const float* ffw_W = (const float*)d_in[4];
  const float* ffw_b = (const float*)d_in[5];
  const float* gates_W = (const float*)d_in[6];
  const float* out_W = (const float*)d_in[7];
  const float* out_b = (const float*)d_in[8];
  float* out = (float*)d_out;

  float* invn = (float*)d_ws;                         // 50048 floats
  float* qn_t = invn + 50048;                         // 128*75*32*4 = 1228800
  float* partial = qn_t + (size_t)NB * NHC * TQ * 4;  // 128*4*32*20 = 327680

  rownorm_kernel<<<(VOCAB + 3) / 4, 256, 0, stream>>>(emb, invn);
  qprep_kernel<<<NB, 256, 0, stream>>>(query, emb, invn, qn_t);
  dim3 grid(NCHUNK, NB);
  cos_topk_kernel<<<grid, 256, 0, stream>>>(doc, emb, invn, qn_t, partial);
  finalize_kernel<<<NB, 64, 0, stream>>>(partial, query, qidf, ffw_W, ffw_b,
                                         gates_W, out_W, out_b, out);
}

// Round 4
// 662.746 us; speedup vs baseline: 2.8106x; 1.0552x over previous
//
#include <hip/hip_runtime.h>
#include <math.h>

#define VOCAB 50000
#define EMB 300
#define NB 128
#define TQ 32
#define TD 4096
#define TOPK 20
#define NCHUNK 4             // blocks per batch along doc axis
#define TOKS_PER_BLOCK 1024  // TD / NCHUNK
#define NTOK 4               // doc tokens per lane
#define NHC 75               // EMB / 4

// ---------------- Kernel 1: per-row inverse norms of emb_table ----------------
__global__ __launch_bounds__(256) void rownorm_kernel(const float* __restrict__ emb,
                                                      float* __restrict__ invn) {
  int row = blockIdx.x * 4 + (threadIdx.x >> 6);
  if (row >= VOCAB) return;
  int lane = threadIdx.x & 63;
  float s = 0.f;
  for (int h = lane; h < EMB; h += 64) {
    float v = emb[row * EMB + h];
    s += v * v;
  }
#pragma unroll
  for (int off = 32; off; off >>= 1) s += __shfl_xor(s, off, 64);
  if (lane == 0) invn[row] = 1.0f / fmaxf(sqrtf(s), 1e-8f);
}

// ---------------- Kernel 1b: normalized query embeddings, transposed ----------------
// qn_t layout: [b][hc][q][4]  (hc = h/4) -> one contiguous 38.4KB slab per b
__global__ __launch_bounds__(256) void qprep_kernel(const int* __restrict__ query,
                                                    const float* __restrict__ emb,
                                                    const float* __restrict__ invn,
                                                    float* __restrict__ qn_t) {
  const int b = blockIdx.x;
  for (int i = (int)threadIdx.x; i < NHC * TQ; i += 256) {
    int hc = i >> 5, q = i & 31;
    int tok = query[b * TQ + q];
    float inv = invn[tok];
    float4 v = *(const float4*)(emb + (size_t)tok * EMB + hc * 4);
    float4 o;
    o.x = v.x * inv; o.y = v.y * inv; o.z = v.z * inv; o.w = v.w * inv;
    *(float4*)(qn_t + (((size_t)b * NHC + hc) * TQ + q) * 4) = o;
  }
}

// ---------------- Kernel 2: cosine + per-block top-k ----------------
// grid = (NCHUNK, NB), block = 256 (4 waves); each lane owns NTOK=4 doc tokens.
// ALL acc indexing is compile-time static (macro-unrolled top-k passes) so the
// 128 accumulators stay in VGPRs (R3's runtime-j indexing spilled them to scratch:
// VGPR=92, 1.2GB HBM fetch. This version must show VGPR>=192, FETCH ~350MB).
__global__ __launch_bounds__(256, 2) void cos_topk_kernel(
    const int* __restrict__ doc, const float* __restrict__ emb,
    const float* __restrict__ invn, const float* __restrict__ qn_t,
    float* __restrict__ partial /* [NB][NCHUNK][TQ][TOPK] */) {
  __shared__ __align__(16) float smem[9600];  // qsh, later reused as costmp
  __shared__ float topv[4][TQ][21];           // per-wave sorted-desc top-20

  float* qsh = smem;
  float (*costmp)[33] = (float (*)[33])smem;  // [wave*64 + tok][q], pad 33

  const int b = blockIdx.y;
  const int chunk = blockIdx.x;
  const int tid = (int)threadIdx.x;
  const int wave = tid >> 6;
  const int lane = tid & 63;

  // stage this batch's normalized query slab into LDS (linear copy, float4)
  {
    const float4* src = (const float4*)(qn_t + (size_t)b * (NHC * TQ * 4));
    float4* dst = (float4*)qsh;
    for (int i = tid; i < NHC * TQ; i += 256) dst[i] = src[i];
  }
  if (lane < TQ) {
#pragma unroll
    for (int k = 0; k < TOPK; ++k) topv[wave][lane][k] = -2.0f;
  }
  __syncthreads();  // qsh ready

  // each lane owns 4 tokens: chunk*1024 + j*256 + tid
  const int t0 = chunk * TOKS_PER_BLOCK;
  const float* __restrict__ drow0 = emb + (size_t)doc[b * TD + t0 + 0 * 256 + tid] * EMB;
  const float* __restrict__ drow1 = emb + (size_t)doc[b * TD + t0 + 1 * 256 + tid] * EMB;
  const float* __restrict__ drow2 = emb + (size_t)doc[b * TD + t0 + 2 * 256 + tid] * EMB;
  const float* __restrict__ drow3 = emb + (size_t)doc[b * TD + t0 + 3 * 256 + tid] * EMB;
  const float invd0 = invn[doc[b * TD + t0 + 0 * 256 + tid]];
  const float invd1 = invn[doc[b * TD + t0 + 1 * 256 + tid]];
  const float invd2 = invn[doc[b * TD + t0 + 2 * 256 + tid]];
  const float invd3 = invn[doc[b * TD + t0 + 3 * 256 + tid]];

  float acc0[TQ], acc1[TQ], acc2[TQ], acc3[TQ];
#pragma unroll
  for (int qi = 0; qi < TQ; ++qi) { acc0[qi] = 0.f; acc1[qi] = 0.f; acc2[qi] = 0.f; acc3[qi] = 0.f; }

  float4 c0 = *(const float4*)(drow0);
  float4 c1 = *(const float4*)(drow1);
  float4 c2 = *(const float4*)(drow2);
  float4 c3 = *(const float4*)(drow3);

  for (int hc = 0; hc < NHC; ++hc) {
    float4 n0, n1, n2, n3;
    if (hc < NHC - 1) {
      n0 = *(const float4*)(drow0 + 4 * (hc + 1));
      n1 = *(const float4*)(drow1 + 4 * (hc + 1));
      n2 = *(const float4*)(drow2 + 4 * (hc + 1));
      n3 = *(const float4*)(drow3 + 4 * (hc + 1));
    }
    const float* __restrict__ qc = qsh + hc * (TQ * 4);
#pragma unroll
    for (int qi = 0; qi < TQ; ++qi) {
      float4 qf = *(const float4*)(qc + qi * 4);  // wave-uniform -> broadcast
      acc0[qi] = fmaf(qf.x, c0.x, fmaf(qf.y, c0.y, fmaf(qf.z, c0.z, fmaf(qf.w, c0.w, acc0[qi]))));
      acc1[qi] = fmaf(qf.x, c1.x, fmaf(qf.y, c1.y, fmaf(qf.z, c1.z, fmaf(qf.w, c1.w, acc1[qi]))));
      acc2[qi] = fmaf(qf.x, c2.x, fmaf(qf.y, c2.y, fmaf(qf.z, c2.z, fmaf(qf.w, c2.w, acc2[qi]))));
      acc3[qi] = fmaf(qf.x, c3.x, fmaf(qf.y, c3.y, fmaf(qf.z, c3.z, fmaf(qf.w, c3.w, acc3[qi]))));
    }
    c0 = n0; c1 = n1; c2 = n2; c3 = n3;
  }

  // 4 macro-unrolled passes: transpose 64 tokens -> merge into wave top-20.
  // __syncthreads() between passes orders this pass's LDS writes after the
  // previous pass's reads (and doubles as a compiler memory fence so passes
  // cannot be interleaved). All indices are compile-time constants.
#define TOPK_PASS(ACC, INVD)                                        \
  __syncthreads();                                                  \
  {                                                                 \
    _Pragma("unroll") for (int qi = 0; qi < TQ; ++qi)               \
        costmp[wave * 64 + lane][qi] = ACC[qi] * INVD;              \
    if (lane < TQ) {                                                \
      const int q = lane;                                           \
      float* tv = &topv[wave][q][0];                                \
      float mn = tv[TOPK - 1];                                      \
      for (int tt = 0; tt < 64; ++tt) {                             \
        float v = costmp[wave * 64 + tt][q];                        \
        if (v > mn) {                                               \
          int p = TOPK - 1;                                         \
          while (p > 0 && tv[p - 1] < v) {                          \
            tv[p] = tv[p - 1];                                      \
            --p;                                                    \
          }                                                         \
          tv[p] = v;                                                \
          mn = tv[TOPK - 1];                                        \
        }                                                           \
      }                                                             \
    }                                                               \
  }

  TOPK_PASS(acc0, invd0)
  TOPK_PASS(acc1, invd1)
  TOPK_PASS(acc2, invd2)
  TOPK_PASS(acc3, invd3)
#undef TOPK_PASS
  __syncthreads();

  // combine 4 wave lists into topv[0]
  if (tid < TQ) {
    const int q = tid;
    float* dst = &topv[0][q][0];
#pragma unroll
    for (int w = 1; w < 4; ++w) {
      for (int k = 0; k < TOPK; ++k) {
        float v = topv[w][q][k];
        if (v <= dst[TOPK - 1]) break;
        int p = TOPK - 1;
        while (p > 0 && dst[p - 1] < v) {
          dst[p] = dst[p - 1];
          --p;
        }
        dst[p] = v;
      }
    }
  }
  __syncthreads();

  for (int i = tid; i < TQ * TOPK; i += 256)
    partial[((size_t)(b * NCHUNK + chunk)) * (TQ * TOPK) + i] =
        topv[0][i / TOPK][i % TOPK];
}

// ---------------- Kernel 3: merge partials, FFW+tanh, gated softmax ----------------
__global__ __launch_bounds__(64) void finalize_kernel(
    const float* __restrict__ partial, const int* __restrict__ query,
    const float* __restrict__ qidf, const float* __restrict__ ffw_W,
    const float* __restrict__ ffw_b, const float* __restrict__ gates_W,
    const float* __restrict__ out_W, const float* __restrict__ out_b,
    float* __restrict__ out) {
  const int b = blockIdx.x;
  const int lane = (int)threadIdx.x;  // 0..63
  float ffw = 0.f;
  float logit = -3e38f;
  if (lane < TQ) {
    const int q = lane;
    int pos[NCHUNK];
#pragma unroll
    for (int c = 0; c < NCHUNK; ++c) pos[c] = 0;
    float s = 0.f;
    for (int k = 0; k < TOPK; ++k) {
      float best = -4.f;
      int bi = 0;
#pragma unroll
      for (int c = 0; c < NCHUNK; ++c) {
        float v = (pos[c] < TOPK)
                      ? partial[((size_t)(b * NCHUNK + c) * TQ + q) * TOPK + pos[c]]
                      : -4.f;
        if (v > best) {
          best = v;
          bi = c;
        }
      }
#pragma unroll
      for (int c = 0; c < NCHUNK; ++c)
        if (c == bi) pos[c]++;
      s += best * ffw_W[k];
    }
    ffw = tanhf(s + ffw_b[0]);
    int tok = query[b * TQ + q];
    logit = qidf[b * TQ + q] * gates_W[0] + (tok == 0 ? -1e7f : 0.f);
  }
  float m = logit;
#pragma unroll
  for (int off = 32; off; off >>= 1) m = fmaxf(m, __shfl_xor(m, off, 64));
  float e = expf(logit - m);
  float num = e * ffw;
  float den = e;
#pragma unroll
  for (int off = 32; off; off >>= 1) {
    num += __shfl_xor(num, off, 64);
    den += __shfl_xor(den, off, 64);
  }
  if (lane == 0) out[b] = (num / den) * out_W[0] + out_b[0];
}

extern "C" void kernel_launch(void* const* d_in, const int* in_sizes, int n_in,
                              void* d_out, int out_size, void* d_ws, size_t ws_size,
                              hipStream_t stream) {
  const int* doc = (const int*)d_in[0];
  const int* query = (const int*)d_in[1];
  const float* qidf = (const float*)d_in[2];
  const float* emb = (const float*)d_in[3];
  const float* ffw_W = (const float*)d_in[4];
  const float* ffw_b = (const float*)d_in[5];
  const float* gates_W = (const float*)d_in[6];
  const float* out_W = (const float*)d_in[7];
  const float* out_b = (const float*)d_in[8];
  float* out = (float*)d_out;

  float* invn = (float*)d_ws;                         // 50048 floats
  float* qn_t = invn + 50048;                         // 128*75*32*4 = 1228800
  float* partial = qn_t + (size_t)NB * NHC * TQ * 4;  // 128*4*32*20 = 327680

  rownorm_kernel<<<(VOCAB + 3) / 4, 256, 0, stream>>>(emb, invn);
  qprep_kernel<<<NB, 256, 0, stream>>>(query, emb, invn, qn_t);
  dim3 grid(NCHUNK, NB);
  cos_topk_kernel<<<grid, 256, 0, stream>>>(doc, emb, invn, qn_t, partial);
  finalize_kernel<<<NB, 64, 0, stream>>>(partial, query, qidf, ffw_W, ffw_b,
                                         gates_W, out_W, out_b, out);
}

// Round 5
// 475.769 us; speedup vs baseline: 3.9152x; 1.3930x over previous
//
#include <hip/hip_runtime.h>
#include <math.h>

#define VOCAB 50000
#define EMB 300
#define NB 128
#define TQ 32
#define TD 4096
#define TOPK 20
#define NCHUNK 16            // blocks per batch along doc axis
#define TOKS_PER_BLOCK 256   // TD / NCHUNK; one token per thread
#define NHC 75               // EMB / 4

// ---------------- Kernel 1: per-row inverse norms of emb_table ----------------
__global__ __launch_bounds__(256) void rownorm_kernel(const float* __restrict__ emb,
                                                      float* __restrict__ invn) {
  int row = blockIdx.x * 4 + (threadIdx.x >> 6);
  if (row >= VOCAB) return;
  int lane = threadIdx.x & 63;
  float s = 0.f;
  for (int h = lane; h < EMB; h += 64) {
    float v = emb[row * EMB + h];
    s += v * v;
  }
#pragma unroll
  for (int off = 32; off; off >>= 1) s += __shfl_xor(s, off, 64);
  if (lane == 0) invn[row] = 1.0f / fmaxf(sqrtf(s), 1e-8f);
}

// ---------------- Kernel 1b: normalized query embeddings, transposed ----------------
// qn_t layout: [b][hc][q][4]  (hc = h/4) -> one contiguous 38.4KB slab per b
__global__ __launch_bounds__(256) void qprep_kernel(const int* __restrict__ query,
                                                    const float* __restrict__ emb,
                                                    const float* __restrict__ invn,
                                                    float* __restrict__ qn_t) {
  const int b = blockIdx.x;
  for (int i = (int)threadIdx.x; i < NHC * TQ; i += 256) {
    int hc = i >> 5, q = i & 31;
    int tok = query[b * TQ + q];
    float inv = invn[tok];
    float4 v = *(const float4*)(emb + (size_t)tok * EMB + hc * 4);
    float4 o;
    o.x = v.x * inv; o.y = v.y * inv; o.z = v.z * inv; o.w = v.w * inv;
    *(float4*)(qn_t + (((size_t)b * NHC + hc) * TQ + q) * 4) = o;
  }
}

// ---------------- Kernel 2: cosine + per-block top-k ----------------
// grid = (NCHUNK, NB), block = 256 (4 waves); each lane owns ONE doc token.
// 32 fp32 accumulators/lane (no fission possible), depth-5 static prefetch
// ring p0..p4 on the gathered doc-row stream, q from LDS broadcast.
// LDS: union{ qsh 38400B ; costmp[4][64][33]=33792B } + topv 10752B = 49152B
// -> 3 blocks/CU (12 waves/CU); launch_bounds(256,3) caps VGPR at ~168.
__global__ __launch_bounds__(256, 3) void cos_topk_kernel(
    const int* __restrict__ doc, const float* __restrict__ emb,
    const float* __restrict__ invn, const float* __restrict__ qn_t,
    float* __restrict__ partial /* [NB][NCHUNK][TQ][TOPK] */) {
  __shared__ __align__(16) float smem[9600];  // qsh, later reused as costmp
  __shared__ float topv[4][TQ][21];           // per-wave sorted-desc top-20

  float* qsh = smem;
  float (*costmp)[33] = (float (*)[33])smem;  // [wave*64 + tok][q], pad 33

  const int b = blockIdx.y;
  const int chunk = blockIdx.x;
  const int tid = (int)threadIdx.x;
  const int wave = tid >> 6;
  const int lane = tid & 63;

  // stage this batch's normalized query slab into LDS (linear copy, float4)
  {
    const float4* src = (const float4*)(qn_t + (size_t)b * (NHC * TQ * 4));
    float4* dst = (float4*)qsh;
    for (int i = tid; i < NHC * TQ; i += 256) dst[i] = src[i];
  }
  if (lane < TQ) {
#pragma unroll
    for (int k = 0; k < TOPK; ++k) topv[wave][lane][k] = -2.0f;
  }
  __syncthreads();  // qsh ready

  const int tok = doc[b * TD + chunk * TOKS_PER_BLOCK + tid];
  const float invd = invn[tok];
  const float* __restrict__ drow = emb + (size_t)tok * EMB;

  float acc[TQ];
#pragma unroll
  for (int qi = 0; qi < TQ; ++qi) acc[qi] = 0.f;

  // depth-5 prefetch ring, all slot names static; 75 = 5*15 rounds
  float4 p0 = *(const float4*)(drow + 0);
  float4 p1 = *(const float4*)(drow + 4);
  float4 p2 = *(const float4*)(drow + 8);
  float4 p3 = *(const float4*)(drow + 12);
  float4 p4 = *(const float4*)(drow + 16);

#define STEP(S, PS)                                                           \
  {                                                                           \
    const float4 d = PS;                                                      \
    PS = *(const float4*)(drow + 4 * (hcb + S + 5));                          \
    const float* __restrict__ qc = qsh + (hcb + S) * (TQ * 4);                \
    _Pragma("unroll") for (int qi = 0; qi < TQ; ++qi) {                       \
      float4 qf = *(const float4*)(qc + qi * 4); /* uniform -> broadcast */   \
      acc[qi] =                                                               \
          fmaf(qf.x, d.x, fmaf(qf.y, d.y, fmaf(qf.z, d.z, fmaf(qf.w, d.w, acc[qi])))); \
    }                                                                         \
  }
#define STEP_LAST(S, PS)                                                      \
  {                                                                           \
    const float4 d = PS;                                                      \
    const float* __restrict__ qc = qsh + (hcb + S) * (TQ * 4);                \
    _Pragma("unroll") for (int qi = 0; qi < TQ; ++qi) {                       \
      float4 qf = *(const float4*)(qc + qi * 4);                              \
      acc[qi] =                                                               \
          fmaf(qf.x, d.x, fmaf(qf.y, d.y, fmaf(qf.z, d.z, fmaf(qf.w, d.w, acc[qi])))); \
    }                                                                         \
  }

#pragma unroll 1
  for (int r = 0; r < 14; ++r) {
    const int hcb = r * 5;
    STEP(0, p0)
    STEP(1, p1)
    STEP(2, p2)
    STEP(3, p3)
    STEP(4, p4)
  }
  {
    const int hcb = 70;  // final round, no reload (avoids OOB past row end)
    STEP_LAST(0, p0)
    STEP_LAST(1, p1)
    STEP_LAST(2, p2)
    STEP_LAST(3, p3)
    STEP_LAST(4, p4)
  }
#undef STEP
#undef STEP_LAST

  __syncthreads();  // all qsh reads done; safe to overwrite with costmp

  // transpose this wave's 64 tokens -> LDS (banks (row+q)%32, conflict-free)
#pragma unroll
  for (int qi = 0; qi < TQ; ++qi) costmp[wave * 64 + lane][qi] = acc[qi] * invd;

  // per-wave top-20 (lane q scans 64 token values; banks (tt+q)%32 distinct)
  if (lane < TQ) {
    const int q = lane;
    float* tv = &topv[wave][q][0];
    float mn = tv[TOPK - 1];
    for (int tt = 0; tt < 64; ++tt) {
      float v = costmp[wave * 64 + tt][q];
      if (v > mn) {
        int p = TOPK - 1;
        while (p > 0 && tv[p - 1] < v) {
          tv[p] = tv[p - 1];
          --p;
        }
        tv[p] = v;
        mn = tv[TOPK - 1];
      }
    }
  }
  __syncthreads();

  // combine 4 wave lists into topv[0]
  if (tid < TQ) {
    const int q = tid;
    float* dst = &topv[0][q][0];
#pragma unroll
    for (int w = 1; w < 4; ++w) {
      for (int k = 0; k < TOPK; ++k) {
        float v = topv[w][q][k];
        if (v <= dst[TOPK - 1]) break;
        int p = TOPK - 1;
        while (p > 0 && dst[p - 1] < v) {
          dst[p] = dst[p - 1];
          --p;
        }
        dst[p] = v;
      }
    }
  }
  __syncthreads();

  for (int i = tid; i < TQ * TOPK; i += 256)
    partial[((size_t)(b * NCHUNK + chunk)) * (TQ * TOPK) + i] =
        topv[0][i / TOPK][i % TOPK];
}

// ---------------- Kernel 3: merge partials, FFW+tanh, gated softmax ----------------
__global__ __launch_bounds__(64) void finalize_kernel(
    const float* __restrict__ partial, const int* __restrict__ query,
    const float* __restrict__ qidf, const float* __restrict__ ffw_W,
    const float* __restrict__ ffw_b, const float* __restrict__ gates_W,
    const float* __restrict__ out_W, const float* __restrict__ out_b,
    float* __restrict__ out) {
  const int b = blockIdx.x;
  const int lane = (int)threadIdx.x;  // 0..63
  float ffw = 0.f;
  float logit = -3e38f;
  if (lane < TQ) {
    const int q = lane;
    int pos[NCHUNK];
#pragma unroll
    for (int c = 0; c < NCHUNK; ++c) pos[c] = 0;
    float s = 0.f;
    for (int k = 0; k < TOPK; ++k) {
      float best = -4.f;
      int bi = 0;
#pragma unroll
      for (int c = 0; c < NCHUNK; ++c) {
        float v = (pos[c] < TOPK)
                      ? partial[((size_t)(b * NCHUNK + c) * TQ + q) * TOPK + pos[c]]
                      : -4.f;
        if (v > best) {
          best = v;
          bi = c;
        }
      }
#pragma unroll
      for (int c = 0; c < NCHUNK; ++c)
        if (c == bi) pos[c]++;
      s += best * ffw_W[k];
    }
    ffw = tanhf(s + ffw_b[0]);
    int tok = query[b * TQ + q];
    logit = qidf[b * TQ + q] * gates_W[0] + (tok == 0 ? -1e7f : 0.f);
  }
  float m = logit;
#pragma unroll
  for (int off = 32; off; off >>= 1) m = fmaxf(m, __shfl_xor(m, off, 64));
  float e = expf(logit - m);
  float num = e * ffw;
  float den = e;
#pragma unroll
  for (int off = 32; off; off >>= 1) {
    num += __shfl_xor(num, off, 64);
    den += __shfl_xor(den, off, 64);
  }
  if (lane == 0) out[b] = (num / den) * out_W[0] + out_b[0];
}

extern "C" void kernel_launch(void* const* d_in, const int* in_sizes, int n_in,
                              void* d_out, int out_size, void* d_ws, size_t ws_size,
                              hipStream_t stream) {
  const int* doc = (const int*)d_in[0];
  const int* query = (const int*)d_in[1];
  const float* qidf = (const float*)d_in[2];
  const float* emb = (const float*)d_in[3];
  const float* ffw_W = (const float*)d_in[4];
  const float* ffw_b = (const float*)d_in[5];
  const float* gates_W = (const float*)d_in[6];
  const float* out_W = (const float*)d_in[7];
  const float* out_b = (const float*)d_in[8];
  float* out = (float*)d_out;

  float* invn = (float*)d_ws;                         // 50048 floats
  float* qn_t = invn + 50048;                         // 128*75*32*4 = 1228800
  float* partial = qn_t + (size_t)NB * NHC * TQ * 4;  // 128*16*32*20 = 1310720

  rownorm_kernel<<<(VOCAB + 3) / 4, 256, 0, stream>>>(emb, invn);
  qprep_kernel<<<NB, 256, 0, stream>>>(query, emb, invn, qn_t);
  dim3 grid(NCHUNK, NB);
  cos_topk_kernel<<<grid, 256, 0, stream>>>(doc, emb, invn, qn_t, partial);
  finalize_kernel<<<NB, 64, 0, stream>>>(partial, query, qidf, ffw_W, ffw_b,
                                         gates_W, out_W, out_b, out);
}